// Round 4
// baseline (637.026 us; speedup 1.0000x reference)
//
#include <hip/hip_runtime.h>

#define NNODES 50000
#define NEDGES 1600000
#define INF 128
#define UNITS 64
#define OUTF 40
#define NLAYERS 6
#define NBUCK 196          // ceil(50000/256), bucket = dst >> 8
#define BCAP 9472          // per-bucket capacity (mean 8192, sigma ~90 -> 14 sigma)
#define CHUNK 8192         // edges per k_bin block
#define NBINB ((NEDGES + CHUNK - 1) / CHUNK)  // 196

__device__ __forceinline__ ushort f2bf(float f) {
  unsigned u = __float_as_uint(f);
  unsigned r = (u + 0x7fffu + ((u >> 16) & 1u)) >> 16;
  return (ushort)r;
}
__device__ __forceinline__ float2 bf2_unpack(unsigned v) {
  float2 r;
  r.x = __uint_as_float(v << 16);
  r.y = __uint_as_float(v & 0xffff0000u);
  return r;
}

// Pass 1: bin edges by dst>>8. packed = (bucket<<24)|(src<<8)|(dst&255)
__global__ void k_bin(const int* __restrict__ src, const int* __restrict__ dst,
                      int* __restrict__ bucket_cursor, unsigned* __restrict__ binned) {
  __shared__ unsigned sh_pack[CHUNK];
  __shared__ int sh_cnt[NBUCK];
  __shared__ int sh_base[NBUCK];
  int tid = threadIdx.x;
  int e0 = blockIdx.x * CHUNK;
  int n = min(CHUNK, NEDGES - e0);
  for (int j = tid; j < NBUCK; j += 256) sh_cnt[j] = 0;
  __syncthreads();
  for (int j = tid; j < n; j += 256) {
    int s = src[e0 + j];
    int d = dst[e0 + j];
    sh_pack[j] = ((unsigned)(d >> 8) << 24) | ((unsigned)s << 8) | (unsigned)(d & 255);
    atomicAdd(&sh_cnt[d >> 8], 1);
  }
  __syncthreads();
  if (tid < NBUCK) {
    sh_base[tid] = atomicAdd(&bucket_cursor[tid], sh_cnt[tid]);
    sh_cnt[tid] = 0;  // reuse as local rank cursor
  }
  __syncthreads();
  for (int j = tid; j < n; j += 256) {
    unsigned p = sh_pack[j];
    int b = p >> 24;
    int r = atomicAdd(&sh_cnt[b], 1);
    int idx = sh_base[b] + r;
    if (idx < BCAP) binned[(size_t)b * BCAP + idx] = p;
  }
}

// Exclusive scan over bucket sizes -> bucket_base
__global__ void k_bucket_scan(const int* __restrict__ bucket_cursor,
                              int* __restrict__ bucket_base) {
  __shared__ int sh[256];
  int tid = threadIdx.x;
  int c = (tid < NBUCK) ? min(bucket_cursor[tid], BCAP) : 0;
  sh[tid] = c;
  __syncthreads();
  for (int off = 1; off < 256; off <<= 1) {
    int t = (tid >= off) ? sh[tid - off] : 0;
    __syncthreads();
    sh[tid] += t;
    __syncthreads();
  }
  if (tid < NBUCK) bucket_base[tid] = sh[tid] - c;
}

// Pass 2: per bucket — LDS hist + scan over 256 local nodes -> row_ptr,
// then place srcs (ushort) within the bucket's L2-resident segment.
__global__ void k_build(const int* __restrict__ bucket_cursor, const int* __restrict__ bucket_base,
                        const unsigned* __restrict__ binned, int* __restrict__ row_ptr,
                        ushort* __restrict__ srcs) {
  __shared__ unsigned sh_packed[BCAP];
  __shared__ int sh_cnt[256];
  __shared__ int sh_off[256];
  int tid = threadIdx.x;
  int b = blockIdx.x;
  int cnt = min(bucket_cursor[b], BCAP);
  int base = bucket_base[b];
  for (int i = tid; i < cnt; i += 256) sh_packed[i] = binned[(size_t)b * BCAP + i];
  sh_cnt[tid] = 0;
  __syncthreads();
  for (int i = tid; i < cnt; i += 256) atomicAdd(&sh_cnt[sh_packed[i] & 255], 1);
  __syncthreads();
  int c = sh_cnt[tid];
  sh_off[tid] = c;
  __syncthreads();
  for (int off = 1; off < 256; off <<= 1) {
    int t = (tid >= off) ? sh_off[tid - off] : 0;
    __syncthreads();
    sh_off[tid] += t;
    __syncthreads();
  }
  int excl = sh_off[tid] - c;
  int node = b * 256 + tid;
  if (node <= NNODES) row_ptr[node] = base + excl;
  sh_off[tid] = excl;  // becomes the placement cursor
  __syncthreads();
  for (int i = tid; i < cnt; i += 256) {
    unsigned p = sh_packed[i];
    int dl = p & 255;
    int pos = atomicAdd(&sh_off[dl], 1);
    srcs[base + pos] = (ushort)((p >> 8) & 0xffff);
  }
}

// z(bf16, half-major: z[half][node][32]) = h @ wl ; s(f32) = h @ ws + (bl+bs+bias)
template <int IN>
__global__ void k_transform(const float* __restrict__ h, const float* __restrict__ wl,
                            const float* __restrict__ ws, const float* __restrict__ bl,
                            const float* __restrict__ bs, const float* __restrict__ bias,
                            ushort* __restrict__ z, float* __restrict__ s) {
  __shared__ float lds_h[16 * IN];
  const float* hbase = h + (size_t)blockIdx.x * 16 * IN;
  for (int idx = threadIdx.x; idx < 16 * IN; idx += 256) lds_h[idx] = hbase[idx];
  __syncthreads();
  int wave = threadIdx.x >> 6;
  int lane = threadIdx.x & 63;
  int nb = blockIdx.x * 16 + wave * 4;
  const float* hl = &lds_h[(wave * 4) * IN];
  float za0 = 0, za1 = 0, za2 = 0, za3 = 0;
  float sa0 = 0, sa1 = 0, sa2 = 0, sa3 = 0;
#pragma unroll 4
  for (int k = 0; k < IN; ++k) {
    float wlv = wl[k * 64 + lane];
    float wsv = ws[k * 64 + lane];
    float h0 = hl[k], h1 = hl[IN + k], h2 = hl[2 * IN + k], h3 = hl[3 * IN + k];
    za0 += h0 * wlv; sa0 += h0 * wsv;
    za1 += h1 * wlv; sa1 += h1 * wsv;
    za2 += h2 * wlv; sa2 += h2 * wsv;
    za3 += h3 * wlv; sa3 += h3 * wsv;
  }
  float c = bl[lane] + bs[lane] + bias[lane];
  int half = lane >> 5;
  int fl = lane & 31;
  ushort* zp = z + (size_t)half * NNODES * 32 + fl;
  zp[(size_t)(nb + 0) * 32] = f2bf(za0); s[(size_t)(nb + 0) * 64 + lane] = sa0 + c;
  zp[(size_t)(nb + 1) * 32] = f2bf(za1); s[(size_t)(nb + 1) * 64 + lane] = sa1 + c;
  zp[(size_t)(nb + 2) * 32] = f2bf(za2); s[(size_t)(nb + 2) * 64 + lane] = sa2 + c;
  zp[(size_t)(nb + 3) * 32] = f2bf(za3); s[(size_t)(nb + 3) * 64 + lane] = sa3 + c;
}

// One feature-half aggregation pass. z_half table = 3.2 MB -> per-XCD-L2 resident.
// block = 256 = 4 waves, one node/wave. 4 lanes/edge (uint4 each = 64 B row),
// 16 edge slots, 2-deep unroll = 32 edges in flight.
// PASS==1 additionally: pull lo-half h from global, JK matvec epilogue.
template <int PASS>
__global__ void k_agg_half(const int* __restrict__ row_ptr, const ushort* __restrict__ srcs,
                           const ushort* __restrict__ z, const float* __restrict__ s,
                           const float* __restrict__ wlast, const float* __restrict__ blast,
                           float* __restrict__ h_out, float* __restrict__ out, int layer) {
  __shared__ float lds_h[4][64];
  int wave = threadIdx.x >> 6;
  int lane = threadIdx.x & 63;
  int g = lane >> 2;   // edge slot (16)
  int fi = lane & 3;   // 16B chunk of the 64B half-row
  int node = blockIdx.x * 4 + wave;
  int start = row_ptr[node];
  int end = row_ptr[node + 1];
  float a0 = 0, a1 = 0, a2 = 0, a3 = 0, a4 = 0, a5 = 0, a6 = 0, a7 = 0;
  const uint4* zv = (const uint4*)(z + (size_t)PASS * NNODES * 32);
  int e = start + g;
  for (; e + 16 < end; e += 32) {
    int s0 = srcs[e];
    int s1 = srcs[e + 16];
    uint4 v0 = zv[(size_t)s0 * 4 + fi];
    uint4 v1 = zv[(size_t)s1 * 4 + fi];
    float2 p0 = bf2_unpack(v0.x), p1 = bf2_unpack(v0.y), p2 = bf2_unpack(v0.z), p3 = bf2_unpack(v0.w);
    float2 q0 = bf2_unpack(v1.x), q1 = bf2_unpack(v1.y), q2 = bf2_unpack(v1.z), q3 = bf2_unpack(v1.w);
    a0 += p0.x + q0.x; a1 += p0.y + q0.y;
    a2 += p1.x + q1.x; a3 += p1.y + q1.y;
    a4 += p2.x + q2.x; a5 += p2.y + q2.y;
    a6 += p3.x + q3.x; a7 += p3.y + q3.y;
  }
  for (; e < end; e += 16) {
    uint4 v = zv[(size_t)srcs[e] * 4 + fi];
    float2 p0 = bf2_unpack(v.x), p1 = bf2_unpack(v.y), p2 = bf2_unpack(v.z), p3 = bf2_unpack(v.w);
    a0 += p0.x; a1 += p0.y; a2 += p1.x; a3 += p1.y;
    a4 += p2.x; a5 += p2.y; a6 += p3.x; a7 += p3.y;
  }
#pragma unroll
  for (int m = 4; m < 64; m <<= 1) {
    a0 += __shfl_xor(a0, m); a1 += __shfl_xor(a1, m);
    a2 += __shfl_xor(a2, m); a3 += __shfl_xor(a3, m);
    a4 += __shfl_xor(a4, m); a5 += __shfl_xor(a5, m);
    a6 += __shfl_xor(a6, m); a7 += __shfl_xor(a7, m);
  }
  if (g == 0) {
    const float4* sp = (const float4*)(s + (size_t)node * 64 + PASS * 32 + fi * 8);
    float4 s0 = sp[0], s1 = sp[1];
    float h0 = fmaxf(a0 + s0.x, 0.f), h1 = fmaxf(a1 + s0.y, 0.f);
    float h2 = fmaxf(a2 + s0.z, 0.f), h3 = fmaxf(a3 + s0.w, 0.f);
    float h4 = fmaxf(a4 + s1.x, 0.f), h5 = fmaxf(a5 + s1.y, 0.f);
    float h6 = fmaxf(a6 + s1.z, 0.f), h7 = fmaxf(a7 + s1.w, 0.f);
    float4* hp = (float4*)(h_out + (size_t)node * 64 + PASS * 32 + fi * 8);
    hp[0] = make_float4(h0, h1, h2, h3);
    hp[1] = make_float4(h4, h5, h6, h7);
    float* lh = &lds_h[wave][PASS * 32 + fi * 8];
    lh[0] = h0; lh[1] = h1; lh[2] = h2; lh[3] = h3;
    lh[4] = h4; lh[5] = h5; lh[6] = h6; lh[7] = h7;
  }
  if (PASS == 1) {
    if (g == 1) {  // lanes 4-7: fetch lo half (written by pass 0, L2-hot)
      const float4* hl4 = (const float4*)(h_out + (size_t)node * 64 + fi * 8);
      float4 l0 = hl4[0], l1 = hl4[1];
      float* lh = &lds_h[wave][fi * 8];
      lh[0] = l0.x; lh[1] = l0.y; lh[2] = l0.z; lh[3] = l0.w;
      lh[4] = l1.x; lh[5] = l1.y; lh[6] = l1.z; lh[7] = l1.w;
    }
    __syncthreads();
    if (lane < OUTF) {
      float o = 0.f;
#pragma unroll 8
      for (int d = 0; d < 64; ++d) o += lds_h[wave][d] * wlast[d * OUTF + lane];
      float prev = (layer == 0) ? blast[lane] : out[(size_t)node * OUTF + lane];
      out[(size_t)node * OUTF + lane] = prev + o;
    }
  }
}

static inline size_t align16(size_t x) { return (x + 15) & ~(size_t)15; }

extern "C" void kernel_launch(void* const* d_in, const int* in_sizes, int n_in,
                              void* d_out, int out_size, void* d_ws, size_t ws_size,
                              hipStream_t stream) {
  const float* x      = (const float*)d_in[0];
  const int*   src    = (const int*)d_in[1];
  const int*   dst    = (const int*)d_in[2];
  const float* w0_lin = (const float*)d_in[3];
  const float* b0_lin = (const float*)d_in[4];
  const float* w0_self= (const float*)d_in[5];
  const float* b0_self= (const float*)d_in[6];
  const float* bias0  = (const float*)d_in[7];
  const float* w_lin  = (const float*)d_in[8];
  const float* b_lin  = (const float*)d_in[9];
  const float* w_self = (const float*)d_in[10];
  const float* b_self = (const float*)d_in[11];
  const float* bias   = (const float*)d_in[12];
  const float* w_last = (const float*)d_in[13];
  const float* b_last = (const float*)d_in[14];
  float* out = (float*)d_out;

  char* w = (char*)d_ws;
  int* row_ptr       = (int*)w;  w += align16((size_t)(NNODES + 1) * 4);
  int* bucket_cursor = (int*)w;  w += align16((size_t)NBUCK * 4);
  int* bucket_base   = (int*)w;  w += align16(256 * 4);
  ushort* srcs       = (ushort*)w; w += align16((size_t)NEDGES * 2);
  // union region: binned (7.43 MB) aliases z (6.4 MB) + head of s; binned is dead
  // before the first k_transform writes z/s (same-stream sequencing).
  char* union_base = w;
  ushort* z = (ushort*)union_base;
  float* s  = (float*)(union_base + align16((size_t)NNODES * 64 * 2));
  float* h  = (float*)(union_base + align16((size_t)NNODES * 64 * 2) + (size_t)NNODES * 64 * 4);
  unsigned* binned = (unsigned*)union_base;

  // ---- CSR build (bucketed) ----
  hipMemsetAsync(bucket_cursor, 0, NBUCK * 4, stream);
  k_bin<<<NBINB, 256, 0, stream>>>(src, dst, bucket_cursor, binned);
  k_bucket_scan<<<1, 256, 0, stream>>>(bucket_cursor, bucket_base);
  k_build<<<NBUCK, 256, 0, stream>>>(bucket_cursor, bucket_base, binned, row_ptr, srcs);

  // ---- layer 0 (IN = 128, input x) ----
  k_transform<INF><<<NNODES / 16, 256, 0, stream>>>(x, w0_lin, w0_self, b0_lin, b0_self,
                                                    bias0, z, s);
  k_agg_half<0><<<NNODES / 4, 256, 0, stream>>>(row_ptr, srcs, z, s, w_last, b_last, h, out, 0);
  k_agg_half<1><<<NNODES / 4, 256, 0, stream>>>(row_ptr, srcs, z, s, w_last, b_last, h, out, 0);

  // ---- layers 1..5 (IN = 64) ----
  for (int l = 1; l < NLAYERS; ++l) {
    int i = l - 1;
    k_transform<UNITS><<<NNODES / 16, 256, 0, stream>>>(
        h, w_lin + (size_t)i * UNITS * UNITS, w_self + (size_t)i * UNITS * UNITS,
        b_lin + (size_t)i * UNITS, b_self + (size_t)i * UNITS, bias + (size_t)i * UNITS, z, s);
    k_agg_half<0><<<NNODES / 4, 256, 0, stream>>>(row_ptr, srcs, z, s,
                                                  w_last + (size_t)l * UNITS * OUTF, b_last,
                                                  h, out, l);
    k_agg_half<1><<<NNODES / 4, 256, 0, stream>>>(row_ptr, srcs, z, s,
                                                  w_last + (size_t)l * UNITS * OUTF, b_last,
                                                  h, out, l);
  }
}

// Round 5
// 348.800 us; speedup vs baseline: 1.8263x; 1.8263x over previous
//
#include <hip/hip_runtime.h>

#define NNODES 50000
#define NEDGES 1600000
#define INF 128
#define UNITS 64
#define OUTF 40
#define NLAYERS 6
#define NBUCK 196          // ceil(50000/256), bucket = dst >> 8
#define BCAP 9472          // per-bucket capacity (mean 8192, 14 sigma)
#define CHUNK 8192         // edges per k_bin block
#define NBINB ((NEDGES + CHUNK - 1) / CHUNK)  // 196

#define WJK_OFS 114688     // byte offset of JK (w_last) blocks inside wbf
#define WBF_BYTES 151552

typedef __attribute__((ext_vector_type(8))) short short8;
typedef __attribute__((ext_vector_type(4))) float f32x4;

__device__ __forceinline__ ushort f2bf(float f) {
  unsigned u = __float_as_uint(f);
  unsigned r = (u + 0x7fffu + ((u >> 16) & 1u)) >> 16;
  return (ushort)r;
}
__device__ __forceinline__ unsigned pack2(float a, float b) {
  return ((unsigned)f2bf(b) << 16) | (unsigned)f2bf(a);
}
__device__ __forceinline__ float2 bf2_unpack(unsigned v) {
  float2 r;
  r.x = __uint_as_float(v << 16);
  r.y = __uint_as_float(v & 0xffff0000u);
  return r;
}

// ---------------- CSR build (unchanged from R3) ----------------
__global__ void k_bin(const int* __restrict__ src, const int* __restrict__ dst,
                      int* __restrict__ bucket_cursor, unsigned* __restrict__ binned) {
  __shared__ unsigned sh_pack[CHUNK];
  __shared__ int sh_cnt[NBUCK];
  __shared__ int sh_base[NBUCK];
  int tid = threadIdx.x;
  int e0 = blockIdx.x * CHUNK;
  int n = min(CHUNK, NEDGES - e0);
  for (int j = tid; j < NBUCK; j += 256) sh_cnt[j] = 0;
  __syncthreads();
  for (int j = tid; j < n; j += 256) {
    int s = src[e0 + j];
    int d = dst[e0 + j];
    sh_pack[j] = ((unsigned)(d >> 8) << 24) | ((unsigned)s << 8) | (unsigned)(d & 255);
    atomicAdd(&sh_cnt[d >> 8], 1);
  }
  __syncthreads();
  if (tid < NBUCK) {
    sh_base[tid] = atomicAdd(&bucket_cursor[tid], sh_cnt[tid]);
    sh_cnt[tid] = 0;
  }
  __syncthreads();
  for (int j = tid; j < n; j += 256) {
    unsigned p = sh_pack[j];
    int b = p >> 24;
    int r = atomicAdd(&sh_cnt[b], 1);
    int idx = sh_base[b] + r;
    if (idx < BCAP) binned[(size_t)b * BCAP + idx] = p;
  }
}

__global__ void k_bucket_scan(const int* __restrict__ bucket_cursor,
                              int* __restrict__ bucket_base) {
  __shared__ int sh[256];
  int tid = threadIdx.x;
  int c = (tid < NBUCK) ? min(bucket_cursor[tid], BCAP) : 0;
  sh[tid] = c;
  __syncthreads();
  for (int off = 1; off < 256; off <<= 1) {
    int t = (tid >= off) ? sh[tid - off] : 0;
    __syncthreads();
    sh[tid] += t;
    __syncthreads();
  }
  if (tid < NBUCK) bucket_base[tid] = sh[tid] - c;
}

__global__ void k_build(const int* __restrict__ bucket_cursor, const int* __restrict__ bucket_base,
                        const unsigned* __restrict__ binned, int* __restrict__ row_ptr,
                        ushort* __restrict__ srcs) {
  __shared__ unsigned sh_packed[BCAP];
  __shared__ int sh_cnt[256];
  __shared__ int sh_off[256];
  int tid = threadIdx.x;
  int b = blockIdx.x;
  int cnt = min(bucket_cursor[b], BCAP);
  int base = bucket_base[b];
  for (int i = tid; i < cnt; i += 256) sh_packed[i] = binned[(size_t)b * BCAP + i];
  sh_cnt[tid] = 0;
  __syncthreads();
  for (int i = tid; i < cnt; i += 256) atomicAdd(&sh_cnt[sh_packed[i] & 255], 1);
  __syncthreads();
  int c = sh_cnt[tid];
  sh_off[tid] = c;
  __syncthreads();
  for (int off = 1; off < 256; off <<= 1) {
    int t = (tid >= off) ? sh_off[tid - off] : 0;
    __syncthreads();
    sh_off[tid] += t;
    __syncthreads();
  }
  int excl = sh_off[tid] - c;
  int node = b * 256 + tid;
  if (node <= NNODES) row_ptr[node] = base + excl;
  sh_off[tid] = excl;
  __syncthreads();
  for (int i = tid; i < cnt; i += 256) {
    unsigned p = sh_packed[i];
    int dl = p & 255;
    int pos = atomicAdd(&sh_off[dl], 1);
    srcs[base + pos] = (ushort)((p >> 8) & 0xffff);
  }
}

// ---------------- weight prep: f32 -> bf16, transposed, pre-swizzled ----------------
// wbf layout (bytes):
//   [0,16384)        wl0^T  [64 c][128 k]
//   [16384,32768)    ws0^T
//   32768 + l*16384  wl_l^T [64][64] (8192) then ws_l^T (8192), l=0..4
//   WJK_OFS + l*6144 wlast_l^T [48 c (pad>=40 zero)][64 k]
// swizzle: byte_in_row ^= (row&7)<<4  (matches ds_read_b128 16B granules)
__global__ void k_prep(const float* __restrict__ w0_lin, const float* __restrict__ w0_self,
                       const float* __restrict__ w_lin, const float* __restrict__ w_self,
                       const float* __restrict__ w_last, char* __restrict__ wbf) {
  int i = blockIdx.x * 256 + threadIdx.x;  // 0..75775
  float val;
  unsigned byte;
  if (i < 16384) {
    int mat = i >> 13, e = i & 8191, c = e >> 7, k = e & 127;
    byte = mat * 16384 + c * 256 + (((unsigned)(k * 2)) ^ ((c & 7) << 4));
    val = (mat ? w0_self : w0_lin)[k * 64 + c];
  } else if (i < 57344) {
    int b = i - 16384;
    int lidx = b / 8192, r = b % 8192, mat = r >> 12, e = r & 4095, c = e >> 6, k = e & 63;
    byte = 32768 + lidx * 16384 + mat * 8192 + c * 128 + (((unsigned)(k * 2)) ^ ((c & 7) << 4));
    val = (mat ? w_self : w_lin)[lidx * 4096 + k * 64 + c];
  } else {
    int b = i - 57344;
    int lidx = b / 3072, r = b % 3072, c = r >> 6, k = r & 63;
    byte = WJK_OFS + lidx * 6144 + c * 128 + (((unsigned)(k * 2)) ^ ((c & 7) << 4));
    val = (c < OUTF) ? w_last[(lidx * 64 + k) * OUTF + c] : 0.f;
  }
  *(ushort*)(wbf + byte) = f2bf(val);
}

// ---------------- MFMA transform ----------------
// Per block: 64 nodes. Wave w: nodes [w*16, w*16+16).
// NEXT: z(bf16)=h@wl, s(bf16)=h@ws+(bl+bs+bias). JK: out (+)= h @ wlast_l (+b_last if INIT).
// MFMA 16x16x32 bf16: A[row=l&15][k=8*(l>>4)+i], B[k][col=l&15], D[row=4*(l>>4)+j][col=l&15].
template <int IN, int NEXT, int JK, int INIT>
__global__ __launch_bounds__(256) void k_transform(
    const void* __restrict__ hin, const char* __restrict__ wbf, int wofs, int jk_l,
    const float* __restrict__ bl, const float* __restrict__ bs, const float* __restrict__ bias,
    const float* __restrict__ b_last, float* __restrict__ out,
    ushort* __restrict__ z, ushort* __restrict__ sout) {
  constexpr int SH = 64 * IN * 2;           // h tile bytes (also one weight mat)
  constexpr int WL = SH;                    // wl at WL, ws at WL+SH (when NEXT)
  constexpr int WJ = NEXT ? 3 * SH : SH;    // jk weights
  constexpr int ZB = WJ + (JK ? 6144 : 0);
  constexpr int SB = ZB + (NEXT ? 8192 : 0);
  constexpr int TOTAL = SB + (NEXT ? 8192 : 0);
  __shared__ alignas(16) char lds[TOTAL];
  int tid = threadIdx.x;
  size_t node0b = (size_t)blockIdx.x * 64;

  // stage h tile -> bf16 swizzled [64][IN]
  if (IN == 128) {
    const float* xin = (const float*)hin;
    for (int q = tid; q < 64 * 16; q += 256) {
      int r = q >> 4, ci = q & 15;
      uint4 v = {0, 0, 0, 0};
      size_t node = node0b + r;
      if (node < NNODES) {
        const float4* sp = (const float4*)(xin + node * 128 + ci * 8);
        float4 f0 = sp[0], f1 = sp[1];
        v.x = pack2(f0.x, f0.y); v.y = pack2(f0.z, f0.w);
        v.z = pack2(f1.x, f1.y); v.w = pack2(f1.z, f1.w);
      }
      *(uint4*)(lds + r * 256 + (((unsigned)(ci * 16)) ^ ((r & 7) << 4))) = v;
    }
  } else {
    const ushort* hb = (const ushort*)hin;
    for (int q = tid; q < 64 * 8; q += 256) {
      int r = q >> 3, ci = q & 7;
      uint4 v = {0, 0, 0, 0};
      size_t node = node0b + r;
      if (node < NNODES) v = ((const uint4*)(hb + node * 64))[ci];
      *(uint4*)(lds + r * 128 + (((unsigned)(ci * 16)) ^ ((r & 7) << 4))) = v;
    }
  }
  if constexpr (NEXT) {
    const uint4* wsrc = (const uint4*)(wbf + wofs);
    for (int q = tid; q < (2 * SH) / 16; q += 256) *(uint4*)(lds + WL + q * 16) = wsrc[q];
  }
  if constexpr (JK) {
    const uint4* jsrc = (const uint4*)(wbf + WJK_OFS + jk_l * 6144);
    for (int q = tid; q < 6144 / 16; q += 256) *(uint4*)(lds + WJ + q * 16) = jsrc[q];
  }
  __syncthreads();

  int l = tid & 63, wave = tid >> 6;
  int r0 = l & 15, kg = l >> 4;
  int rr = wave * 16 + r0;
  size_t node0w = node0b + wave * 16;

  f32x4 az[4], as_[4], ao[3];
#pragma unroll
  for (int n = 0; n < 4; ++n) { az[n] = (f32x4){0, 0, 0, 0}; as_[n] = (f32x4){0, 0, 0, 0}; }
  if constexpr (JK) {
#pragma unroll
    for (int n = 0; n < 3; ++n) {
      int c = n * 16 + r0;
#pragma unroll
      for (int j = 0; j < 4; ++j) {
        float v = 0.f;
        if constexpr (INIT) {
          if (c < OUTF) v = b_last[c];
        } else {
          size_t node = node0w + 4 * kg + j;
          if (c < OUTF && node < NNODES) v = out[node * OUTF + c];
        }
        ao[n][j] = v;
      }
    }
  }

#pragma unroll
  for (int kk = 0; kk < IN / 32; ++kk) {
    unsigned ak = kk * 64 + 16 * kg;
    short8 a = *(const short8*)(lds + rr * (IN * 2) + (ak ^ ((rr & 7) << 4)));
    if constexpr (NEXT) {
#pragma unroll
      for (int n = 0; n < 4; ++n) {
        int c = n * 16 + r0;
        unsigned cofs = c * (IN * 2) + (ak ^ ((c & 7) << 4));
        short8 bz = *(const short8*)(lds + WL + cofs);
        short8 bw = *(const short8*)(lds + WL + SH + cofs);
        az[n] = __builtin_amdgcn_mfma_f32_16x16x32_bf16(a, bz, az[n], 0, 0, 0);
        as_[n] = __builtin_amdgcn_mfma_f32_16x16x32_bf16(a, bw, as_[n], 0, 0, 0);
      }
    }
    if constexpr (JK) {
#pragma unroll
      for (int n = 0; n < 3; ++n) {
        int c = n * 16 + r0;
        short8 bj = *(const short8*)(lds + WJ + c * 128 + (ak ^ ((c & 7) << 4)));
        ao[n] = __builtin_amdgcn_mfma_f32_16x16x32_bf16(a, bj, ao[n], 0, 0, 0);
      }
    }
  }

  if constexpr (JK) {
#pragma unroll
    for (int n = 0; n < 3; ++n) {
      int c = n * 16 + r0;
      if (c < OUTF) {
#pragma unroll
        for (int j = 0; j < 4; ++j) {
          size_t node = node0w + 4 * kg + j;
          if (node < NNODES) out[node * OUTF + c] = ao[n][j];
        }
      }
    }
  }
  if constexpr (NEXT) {
    ushort* zb = (ushort*)(lds + ZB);
    ushort* sb = (ushort*)(lds + SB);
#pragma unroll
    for (int n = 0; n < 4; ++n) {
      int c = n * 16 + r0;
      float cc = bl[c] + bs[c] + bias[c];
#pragma unroll
      for (int j = 0; j < 4; ++j) {
        int rw = wave * 16 + 4 * kg + j;
        zb[rw * 64 + c] = f2bf(az[n][j]);
        sb[rw * 64 + c] = f2bf(as_[n][j] + cc);
      }
    }
    __syncthreads();
    for (int q = tid; q < 512; q += 256) {
      int r = q >> 3;
      if (node0b + r < NNODES) {
        ((uint4*)((char*)z + node0b * 128))[q] = *(const uint4*)(lds + ZB + q * 16);
        ((uint4*)((char*)sout + node0b * 128))[q] = *(const uint4*)(lds + SB + q * 16);
      }
    }
  }
}

// ---------------- aggregate (R3 structure; bf16 s in, bf16 h out, no epilogue) ----------------
__global__ void k_aggregate(const int* __restrict__ row_ptr, const ushort* __restrict__ srcs,
                            const ushort* __restrict__ z, const ushort* __restrict__ s,
                            ushort* __restrict__ h_out) {
  int wave = threadIdx.x >> 6;
  int lane = threadIdx.x & 63;
  int g = lane >> 3;   // edge slot within wave
  int fi = lane & 7;   // 16B chunk of the 128B row
  int node = blockIdx.x * 4 + wave;
  int start = row_ptr[node];
  int end = row_ptr[node + 1];
  float a0 = 0, a1 = 0, a2 = 0, a3 = 0, a4 = 0, a5 = 0, a6 = 0, a7 = 0;
  const uint4* zv = (const uint4*)z;
  int e = start + g;
  for (; e + 8 < end; e += 16) {
    int s0 = srcs[e];
    int s1 = srcs[e + 8];
    uint4 v0 = zv[(size_t)s0 * 8 + fi];
    uint4 v1 = zv[(size_t)s1 * 8 + fi];
    float2 p0 = bf2_unpack(v0.x), p1 = bf2_unpack(v0.y), p2 = bf2_unpack(v0.z), p3 = bf2_unpack(v0.w);
    float2 q0 = bf2_unpack(v1.x), q1 = bf2_unpack(v1.y), q2 = bf2_unpack(v1.z), q3 = bf2_unpack(v1.w);
    a0 += p0.x + q0.x; a1 += p0.y + q0.y;
    a2 += p1.x + q1.x; a3 += p1.y + q1.y;
    a4 += p2.x + q2.x; a5 += p2.y + q2.y;
    a6 += p3.x + q3.x; a7 += p3.y + q3.y;
  }
  if (e < end) {
    uint4 v = zv[(size_t)srcs[e] * 8 + fi];
    float2 p0 = bf2_unpack(v.x), p1 = bf2_unpack(v.y), p2 = bf2_unpack(v.z), p3 = bf2_unpack(v.w);
    a0 += p0.x; a1 += p0.y; a2 += p1.x; a3 += p1.y;
    a4 += p2.x; a5 += p2.y; a6 += p3.x; a7 += p3.y;
  }
#pragma unroll
  for (int m = 8; m < 64; m <<= 1) {
    a0 += __shfl_xor(a0, m); a1 += __shfl_xor(a1, m);
    a2 += __shfl_xor(a2, m); a3 += __shfl_xor(a3, m);
    a4 += __shfl_xor(a4, m); a5 += __shfl_xor(a5, m);
    a6 += __shfl_xor(a6, m); a7 += __shfl_xor(a7, m);
  }
  if (g == 0) {
    uint4 sv = ((const uint4*)s)[node * 8 + fi];
    float2 s0 = bf2_unpack(sv.x), s1 = bf2_unpack(sv.y), s2 = bf2_unpack(sv.z), s3 = bf2_unpack(sv.w);
    float h0 = fmaxf(a0 + s0.x, 0.f), h1 = fmaxf(a1 + s0.y, 0.f);
    float h2 = fmaxf(a2 + s1.x, 0.f), h3 = fmaxf(a3 + s1.y, 0.f);
    float h4 = fmaxf(a4 + s2.x, 0.f), h5 = fmaxf(a5 + s2.y, 0.f);
    float h6 = fmaxf(a6 + s3.x, 0.f), h7 = fmaxf(a7 + s3.y, 0.f);
    uint4 hp;
    hp.x = pack2(h0, h1); hp.y = pack2(h2, h3);
    hp.z = pack2(h4, h5); hp.w = pack2(h6, h7);
    ((uint4*)h_out)[node * 8 + fi] = hp;
  }
}

static inline size_t align16(size_t x) { return (x + 15) & ~(size_t)15; }

extern "C" void kernel_launch(void* const* d_in, const int* in_sizes, int n_in,
                              void* d_out, int out_size, void* d_ws, size_t ws_size,
                              hipStream_t stream) {
  const float* x      = (const float*)d_in[0];
  const int*   src    = (const int*)d_in[1];
  const int*   dst    = (const int*)d_in[2];
  const float* w0_lin = (const float*)d_in[3];
  const float* b0_lin = (const float*)d_in[4];
  const float* w0_self= (const float*)d_in[5];
  const float* b0_self= (const float*)d_in[6];
  const float* bias0  = (const float*)d_in[7];
  const float* w_lin  = (const float*)d_in[8];
  const float* b_lin  = (const float*)d_in[9];
  const float* w_self = (const float*)d_in[10];
  const float* b_self = (const float*)d_in[11];
  const float* bias   = (const float*)d_in[12];
  const float* w_last = (const float*)d_in[13];
  const float* b_last = (const float*)d_in[14];
  float* out = (float*)d_out;

  char* w = (char*)d_ws;
  int* row_ptr       = (int*)w;  w += align16((size_t)(NNODES + 1) * 4);
  int* bucket_cursor = (int*)w;  w += align16((size_t)NBUCK * 4);
  int* bucket_base   = (int*)w;  w += align16(1024);
  ushort* srcs       = (ushort*)w; w += align16((size_t)NEDGES * 2);
  // union region: binned (7.43 MB) aliases z (6.4 MB) + s (6.4 MB); binned is dead
  // before the first k_transform writes z/s (same-stream sequencing).
  char* zs_base = w;
  ushort* z = (ushort*)zs_base;
  ushort* s = (ushort*)(zs_base + (size_t)NNODES * 64 * 2);
  unsigned* binned = (unsigned*)zs_base;
  w += (size_t)NNODES * 64 * 2 * 2;
  ushort* h = (ushort*)w; w += (size_t)NNODES * 64 * 2;
  char* wbf = w; w += WBF_BYTES;

  // ---- weight prep + CSR build ----
  hipMemsetAsync(bucket_cursor, 0, NBUCK * 4, stream);
  k_prep<<<296, 256, 0, stream>>>(w0_lin, w0_self, w_lin, w_self, w_last, wbf);
  k_bin<<<NBINB, 256, 0, stream>>>(src, dst, bucket_cursor, binned);
  k_bucket_scan<<<1, 256, 0, stream>>>(bucket_cursor, bucket_base);
  k_build<<<NBUCK, 256, 0, stream>>>(bucket_cursor, bucket_base, binned, row_ptr, srcs);

  const int TGRID = (NNODES + 63) / 64;  // 782

  // ---- layer 0 transform (x, IN=128, no JK) ----
  k_transform<128, 1, 0, 0><<<TGRID, 256, 0, stream>>>(
      x, wbf, 0, 0, b0_lin, b0_self, bias0, nullptr, nullptr, z, s);

  for (int l = 0; l < NLAYERS; ++l) {
    k_aggregate<<<NNODES / 4, 256, 0, stream>>>(row_ptr, srcs, z, s, h);
    if (l < NLAYERS - 1) {
      int wofs = 32768 + l * 16384;
      const float* bl_p = b_lin + (size_t)l * 64;
      const float* bs_p = b_self + (size_t)l * 64;
      const float* bi_p = bias + (size_t)l * 64;
      if (l == 0)
        k_transform<64, 1, 1, 1><<<TGRID, 256, 0, stream>>>(
            h, wbf, wofs, 0, bl_p, bs_p, bi_p, b_last, out, z, s);
      else
        k_transform<64, 1, 1, 0><<<TGRID, 256, 0, stream>>>(
            h, wbf, wofs, l, bl_p, bs_p, bi_p, nullptr, out, z, s);
    }
  }
  // JK for h_5 (no z/s production)
  k_transform<64, 0, 1, 0><<<TGRID, 256, 0, stream>>>(
      h, wbf, 0, 5, nullptr, nullptr, nullptr, nullptr, out, nullptr, nullptr);
}

// Round 6
// 335.274 us; speedup vs baseline: 1.9000x; 1.0403x over previous
//
#include <hip/hip_runtime.h>

#define NNODES 50000
#define NEDGES 1600000
#define INF 128
#define UNITS 64
#define OUTF 40
#define NLAYERS 6
#define NBUCK 196          // ceil(50000/256), bucket = dst >> 8
#define BCAP 9472          // per-bucket capacity (mean 8192, 14 sigma)
#define CHUNK 8192         // edges per k_bin block
#define NBINB ((NEDGES + CHUNK - 1) / CHUNK)  // 196

#define WJK_OFS 114688     // byte offset of JK (w_last) blocks inside wbf
#define WBF_BYTES (114688 + 6 * 6144)

typedef __attribute__((ext_vector_type(8))) short short8;
typedef __attribute__((ext_vector_type(4))) float f32x4;

__device__ __forceinline__ ushort f2bf(float f) {
  unsigned u = __float_as_uint(f);
  unsigned r = (u + 0x7fffu + ((u >> 16) & 1u)) >> 16;
  return (ushort)r;
}
__device__ __forceinline__ unsigned pack2(float a, float b) {
  return ((unsigned)f2bf(b) << 16) | (unsigned)f2bf(a);
}
__device__ __forceinline__ float2 bf2_unpack(unsigned v) {
  float2 r;
  r.x = __uint_as_float(v << 16);
  r.y = __uint_as_float(v & 0xffff0000u);
  return r;
}

// ---------------- CSR build ----------------
__global__ void k_bin(const int* __restrict__ src, const int* __restrict__ dst,
                      int* __restrict__ bucket_cursor, unsigned* __restrict__ binned) {
  __shared__ unsigned sh_pack[CHUNK];
  __shared__ int sh_cnt[NBUCK];
  __shared__ int sh_base[NBUCK];
  int tid = threadIdx.x;
  int e0 = blockIdx.x * CHUNK;
  int n = min(CHUNK, NEDGES - e0);
  for (int j = tid; j < NBUCK; j += 256) sh_cnt[j] = 0;
  __syncthreads();
  for (int j = tid; j < n; j += 256) {
    int s = src[e0 + j];
    int d = dst[e0 + j];
    sh_pack[j] = ((unsigned)(d >> 8) << 24) | ((unsigned)s << 8) | (unsigned)(d & 255);
    atomicAdd(&sh_cnt[d >> 8], 1);
  }
  __syncthreads();
  if (tid < NBUCK) {
    sh_base[tid] = atomicAdd(&bucket_cursor[tid], sh_cnt[tid]);
    sh_cnt[tid] = 0;
  }
  __syncthreads();
  for (int j = tid; j < n; j += 256) {
    unsigned p = sh_pack[j];
    int b = p >> 24;
    int r = atomicAdd(&sh_cnt[b], 1);
    int idx = sh_base[b] + r;
    if (idx < BCAP) binned[(size_t)b * BCAP + idx] = p;
  }
}

__global__ void k_bucket_scan(const int* __restrict__ bucket_cursor,
                              int* __restrict__ bucket_base) {
  __shared__ int sh[256];
  int tid = threadIdx.x;
  int c = (tid < NBUCK) ? min(bucket_cursor[tid], BCAP) : 0;
  sh[tid] = c;
  __syncthreads();
  for (int off = 1; off < 256; off <<= 1) {
    int t = (tid >= off) ? sh[tid - off] : 0;
    __syncthreads();
    sh[tid] += t;
    __syncthreads();
  }
  if (tid < NBUCK) bucket_base[tid] = sh[tid] - c;
}

__global__ void k_build(const int* __restrict__ bucket_cursor, const int* __restrict__ bucket_base,
                        const unsigned* __restrict__ binned, int* __restrict__ row_ptr,
                        ushort* __restrict__ srcs) {
  __shared__ unsigned sh_packed[BCAP];
  __shared__ int sh_cnt[256];
  __shared__ int sh_off[256];
  int tid = threadIdx.x;
  int b = blockIdx.x;
  int cnt = min(bucket_cursor[b], BCAP);
  int base = bucket_base[b];
  for (int i = tid; i < cnt; i += 256) sh_packed[i] = binned[(size_t)b * BCAP + i];
  sh_cnt[tid] = 0;
  __syncthreads();
  for (int i = tid; i < cnt; i += 256) atomicAdd(&sh_cnt[sh_packed[i] & 255], 1);
  __syncthreads();
  int c = sh_cnt[tid];
  sh_off[tid] = c;
  __syncthreads();
  for (int off = 1; off < 256; off <<= 1) {
    int t = (tid >= off) ? sh_off[tid - off] : 0;
    __syncthreads();
    sh_off[tid] += t;
    __syncthreads();
  }
  int excl = sh_off[tid] - c;
  int node = b * 256 + tid;
  if (node <= NNODES) row_ptr[node] = base + excl;
  sh_off[tid] = excl;
  __syncthreads();
  for (int i = tid; i < cnt; i += 256) {
    unsigned p = sh_packed[i];
    int dl = p & 255;
    int pos = atomicAdd(&sh_off[dl], 1);
    srcs[base + pos] = (ushort)((p >> 8) & 0xffff);
  }
}

// ---------------- weight prep: f32 -> bf16 transposed [c][k], UNswizzled ----------------
// [0,16384) wl0^T [64][128]; [16384,32768) ws0^T;
// 32768+k*16384: wl_k^T [64][64] then ws_k^T, k=0..4;
// WJK_OFS+k*6144: wlast_k^T [48 (pad zero)][64], k=0..5
__global__ void k_prep(const float* __restrict__ w0_lin, const float* __restrict__ w0_self,
                       const float* __restrict__ w_lin, const float* __restrict__ w_self,
                       const float* __restrict__ w_last, char* __restrict__ wbf) {
  int i = blockIdx.x * 256 + threadIdx.x;  // 0..75775
  float val;
  unsigned byte;
  if (i < 16384) {
    int mat = i >> 13, e = i & 8191, c = e >> 7, k = e & 127;
    byte = mat * 16384 + c * 256 + k * 2;
    val = (mat ? w0_self : w0_lin)[k * 64 + c];
  } else if (i < 57344) {
    int b = i - 16384;
    int lidx = b / 8192, r = b % 8192, mat = r >> 12, e = r & 4095, c = e >> 6, k = e & 63;
    byte = 32768 + lidx * 16384 + mat * 8192 + c * 128 + k * 2;
    val = (mat ? w_self : w_lin)[lidx * 4096 + k * 64 + c];
  } else {
    int b = i - 57344;
    int lidx = b / 3072, r = b % 3072, c = r >> 6, k = r & 63;
    byte = WJK_OFS + lidx * 6144 + c * 128 + k * 2;
    val = (c < OUTF) ? w_last[(lidx * 64 + k) * OUTF + c] : 0.f;
  }
  *(ushort*)(wbf + byte) = f2bf(val);
}

// ---------------- layer-0 transform (x f32 -> z0,s0), B from global ----------------
__global__ __launch_bounds__(256) void k_transform0(
    const float* __restrict__ x, const char* __restrict__ wbf,
    const float* __restrict__ bl, const float* __restrict__ bs, const float* __restrict__ bias,
    ushort* __restrict__ z, ushort* __restrict__ sout) {
  __shared__ alignas(16) char lds[32768];  // A 16K | zst 8K | sst 8K
  int tid = threadIdx.x;
  size_t node0b = (size_t)blockIdx.x * 64;
  for (int q = tid; q < 1024; q += 256) {
    int r = q >> 4, ci = q & 15;
    uint4 v = {0, 0, 0, 0};
    size_t node = node0b + r;
    if (node < NNODES) {
      const float4* sp = (const float4*)(x + node * 128 + ci * 8);
      float4 f0 = sp[0], f1 = sp[1];
      v.x = pack2(f0.x, f0.y); v.y = pack2(f0.z, f0.w);
      v.z = pack2(f1.x, f1.y); v.w = pack2(f1.z, f1.w);
    }
    *(uint4*)(lds + r * 256 + (((unsigned)(ci * 16)) ^ ((r & 7) << 4))) = v;
  }
  __syncthreads();
  int lane = tid & 63, wave = tid >> 6;
  int r0 = lane & 15, kg = lane >> 4;
  int rr = wave * 16 + r0;
  f32x4 az[4], as_[4];
#pragma unroll
  for (int n = 0; n < 4; ++n) { az[n] = (f32x4){0, 0, 0, 0}; as_[n] = (f32x4){0, 0, 0, 0}; }
#pragma unroll
  for (int kk = 0; kk < 4; ++kk) {
    unsigned ak = kk * 64 + kg * 16;
    short8 a = *(const short8*)(lds + rr * 256 + (ak ^ ((rr & 7) << 4)));
#pragma unroll
    for (int n = 0; n < 4; ++n) {
      int c = n * 16 + r0;
      short8 bz = *(const short8*)(wbf + c * 256 + ak);
      short8 bw = *(const short8*)(wbf + 16384 + c * 256 + ak);
      az[n] = __builtin_amdgcn_mfma_f32_16x16x32_bf16(a, bz, az[n], 0, 0, 0);
      as_[n] = __builtin_amdgcn_mfma_f32_16x16x32_bf16(a, bw, as_[n], 0, 0, 0);
    }
  }
  ushort* zst = (ushort*)(lds + 16384);
  ushort* sst = (ushort*)(lds + 24576);
#pragma unroll
  for (int n = 0; n < 4; ++n) {
    int c = n * 16 + r0;
    float cc = bl[c] + bs[c] + bias[c];
#pragma unroll
    for (int j = 0; j < 4; ++j) {
      int rw = wave * 16 + 4 * kg + j;
      zst[rw * 64 + c] = f2bf(az[n][j]);
      sst[rw * 64 + c] = f2bf(as_[n][j] + cc);
    }
  }
  __syncthreads();
  for (int q = tid; q < 512; q += 256) {
    int r = q >> 3;
    if (node0b + r < NNODES) {
      ((uint4*)z)[node0b * 8 + q] = *(const uint4*)(lds + 16384 + q * 16);
      ((uint4*)sout)[node0b * 8 + q] = *(const uint4*)(lds + 24576 + q * 16);
    }
  }
}

// ---------------- fused layer: aggregate + (JK, next transform) ----------------
// block = 256 thr = 4 waves, 16 nodes. Phase A: R3 gather (4 nodes/wave) -> h in LDS A-tile.
// Phase B: MFMA with B-frags straight from global (L1-hot weights).
template <int NEXT, int INIT>
__global__ __launch_bounds__(256) void k_fused(
    const int* __restrict__ row_ptr, const ushort* __restrict__ srcs,
    const ushort* __restrict__ z_prev, const ushort* __restrict__ s_io,
    const char* __restrict__ wbf, int wl_ofs, int jk_l,
    const float* __restrict__ bl, const float* __restrict__ bs, const float* __restrict__ bias,
    const float* __restrict__ b_last, float* __restrict__ out,
    ushort* __restrict__ z_next) {
  __shared__ alignas(16) char lds[NEXT ? 6144 : 2048];  // A 2K | zst 2K | sst 2K
  int tid = threadIdx.x;
  int wave = tid >> 6, lane = tid & 63;
  int g = lane >> 3, fi = lane & 7;
  int base = blockIdx.x * 16;
  const uint4* zv = (const uint4*)z_prev;

  // ---- phase A ----
  for (int q = 0; q < 4; ++q) {
    int node = base + wave * 4 + q;
    int start = row_ptr[node];
    int end = row_ptr[node + 1];
    float a0 = 0, a1 = 0, a2 = 0, a3 = 0, a4 = 0, a5 = 0, a6 = 0, a7 = 0;
    int e = start + g;
    for (; e + 8 < end; e += 16) {
      int s0 = srcs[e];
      int s1 = srcs[e + 8];
      uint4 v0 = zv[(size_t)s0 * 8 + fi];
      uint4 v1 = zv[(size_t)s1 * 8 + fi];
      float2 p0 = bf2_unpack(v0.x), p1 = bf2_unpack(v0.y), p2 = bf2_unpack(v0.z), p3 = bf2_unpack(v0.w);
      float2 q0 = bf2_unpack(v1.x), q1 = bf2_unpack(v1.y), q2 = bf2_unpack(v1.z), q3 = bf2_unpack(v1.w);
      a0 += p0.x + q0.x; a1 += p0.y + q0.y;
      a2 += p1.x + q1.x; a3 += p1.y + q1.y;
      a4 += p2.x + q2.x; a5 += p2.y + q2.y;
      a6 += p3.x + q3.x; a7 += p3.y + q3.y;
    }
    if (e < end) {
      uint4 v = zv[(size_t)srcs[e] * 8 + fi];
      float2 p0 = bf2_unpack(v.x), p1 = bf2_unpack(v.y), p2 = bf2_unpack(v.z), p3 = bf2_unpack(v.w);
      a0 += p0.x; a1 += p0.y; a2 += p1.x; a3 += p1.y;
      a4 += p2.x; a5 += p2.y; a6 += p3.x; a7 += p3.y;
    }
#pragma unroll
    for (int m = 8; m < 64; m <<= 1) {
      a0 += __shfl_xor(a0, m); a1 += __shfl_xor(a1, m);
      a2 += __shfl_xor(a2, m); a3 += __shfl_xor(a3, m);
      a4 += __shfl_xor(a4, m); a5 += __shfl_xor(a5, m);
      a6 += __shfl_xor(a6, m); a7 += __shfl_xor(a7, m);
    }
    if (g == 0) {
      uint4 sv = ((const uint4*)s_io)[(size_t)node * 8 + fi];
      float2 s0 = bf2_unpack(sv.x), s1 = bf2_unpack(sv.y), s2 = bf2_unpack(sv.z), s3 = bf2_unpack(sv.w);
      float h0 = fmaxf(a0 + s0.x, 0.f), h1 = fmaxf(a1 + s0.y, 0.f);
      float h2 = fmaxf(a2 + s1.x, 0.f), h3 = fmaxf(a3 + s1.y, 0.f);
      float h4 = fmaxf(a4 + s2.x, 0.f), h5 = fmaxf(a5 + s2.y, 0.f);
      float h6 = fmaxf(a6 + s3.x, 0.f), h7 = fmaxf(a7 + s3.y, 0.f);
      int r = wave * 4 + q;
      uint4 hp;
      hp.x = pack2(h0, h1); hp.y = pack2(h2, h3);
      hp.z = pack2(h4, h5); hp.w = pack2(h6, h7);
      *(uint4*)(lds + r * 128 + (((unsigned)(fi * 16)) ^ ((r & 7) << 4))) = hp;
    }
  }
  __syncthreads();

  // ---- phase B ----
  int r0 = lane & 15, kg = lane >> 4;
  int c = wave * 16 + r0;
  f32x4 az = {0, 0, 0, 0}, as_ = {0, 0, 0, 0}, ao = {0, 0, 0, 0};
  if (wave < 3) {
    if constexpr (INIT) {
      float bi = (c < OUTF) ? b_last[c] : 0.f;
      ao = (f32x4){bi, bi, bi, bi};
    } else {
      if (c < OUTF) {
#pragma unroll
        for (int j = 0; j < 4; ++j) ao[j] = out[(size_t)(base + 4 * kg + j) * OUTF + c];
      }
    }
  }
#pragma unroll
  for (int kk = 0; kk < 2; ++kk) {
    unsigned ak = kk * 64 + kg * 16;
    short8 a = *(const short8*)(lds + r0 * 128 + (ak ^ ((r0 & 7) << 4)));
    if constexpr (NEXT) {
      short8 bz = *(const short8*)(wbf + wl_ofs + c * 128 + ak);
      short8 bw = *(const short8*)(wbf + wl_ofs + 8192 + c * 128 + ak);
      az = __builtin_amdgcn_mfma_f32_16x16x32_bf16(a, bz, az, 0, 0, 0);
      as_ = __builtin_amdgcn_mfma_f32_16x16x32_bf16(a, bw, as_, 0, 0, 0);
    }
    if (wave < 3) {
      short8 bj = *(const short8*)(wbf + WJK_OFS + jk_l * 6144 + c * 128 + ak);
      ao = __builtin_amdgcn_mfma_f32_16x16x32_bf16(a, bj, ao, 0, 0, 0);
    }
  }
  if (wave < 3 && c < OUTF) {
#pragma unroll
    for (int j = 0; j < 4; ++j) out[(size_t)(base + 4 * kg + j) * OUTF + c] = ao[j];
  }
  if constexpr (NEXT) {
    ushort* zst = (ushort*)(lds + 2048);
    ushort* sst = (ushort*)(lds + 4096);
    float cc = bl[c] + bs[c] + bias[c];
#pragma unroll
    for (int j = 0; j < 4; ++j) {
      int rw = 4 * kg + j;
      zst[rw * 64 + c] = f2bf(az[j]);
      sst[rw * 64 + c] = f2bf(as_[j] + cc);
    }
    __syncthreads();
    if (tid < 128) {
      ((uint4*)z_next)[(size_t)base * 8 + tid] = *(const uint4*)(lds + 2048 + tid * 16);
    } else {
      int q = tid - 128;
      ((uint4*)s_io)[(size_t)base * 8 + q] = *(const uint4*)(lds + 4096 + q * 16);
    }
  }
}

static inline size_t align16(size_t x) { return (x + 15) & ~(size_t)15; }

extern "C" void kernel_launch(void* const* d_in, const int* in_sizes, int n_in,
                              void* d_out, int out_size, void* d_ws, size_t ws_size,
                              hipStream_t stream) {
  const float* x      = (const float*)d_in[0];
  const int*   src    = (const int*)d_in[1];
  const int*   dst    = (const int*)d_in[2];
  const float* w0_lin = (const float*)d_in[3];
  const float* b0_lin = (const float*)d_in[4];
  const float* w0_self= (const float*)d_in[5];
  const float* b0_self= (const float*)d_in[6];
  const float* bias0  = (const float*)d_in[7];
  const float* w_lin  = (const float*)d_in[8];
  const float* b_lin  = (const float*)d_in[9];
  const float* w_self = (const float*)d_in[10];
  const float* b_self = (const float*)d_in[11];
  const float* bias   = (const float*)d_in[12];
  const float* w_last = (const float*)d_in[13];
  const float* b_last = (const float*)d_in[14];
  float* out = (float*)d_out;

  char* w = (char*)d_ws;
  int* row_ptr       = (int*)w;  w += align16((size_t)(NNODES + 1) * 4);
  int* bucket_cursor = (int*)w;  w += align16((size_t)NBUCK * 4);
  int* bucket_base   = (int*)w;  w += align16(1024);
  ushort* srcs       = (ushort*)w; w += align16((size_t)NEDGES * 2);
  // binned (7.43 MB) aliases zA+zB (12.8 MB); binned dead before transform0 writes zA.
  char* zbase = w;
  ushort* zA = (ushort*)zbase;
  ushort* zB = (ushort*)(zbase + (size_t)NNODES * 64 * 2);
  unsigned* binned = (unsigned*)zbase;
  w += (size_t)NNODES * 64 * 2 * 2;
  ushort* s = (ushort*)w; w += (size_t)NNODES * 64 * 2;
  char* wbf = w; w += WBF_BYTES;

  hipMemsetAsync(bucket_cursor, 0, NBUCK * 4, stream);
  k_prep<<<296, 256, 0, stream>>>(w0_lin, w0_self, w_lin, w_self, w_last, wbf);
  k_bin<<<NBINB, 256, 0, stream>>>(src, dst, bucket_cursor, binned);
  k_bucket_scan<<<1, 256, 0, stream>>>(bucket_cursor, bucket_base);
  k_build<<<NBUCK, 256, 0, stream>>>(bucket_cursor, bucket_base, binned, row_ptr, srcs);

  k_transform0<<<(NNODES + 63) / 64, 256, 0, stream>>>(x, wbf, b0_lin, b0_self, bias0, zA, s);

  const int FGRID = NNODES / 16;  // 3125
  for (int k = 0; k < NLAYERS; ++k) {
    ushort* zin = (k % 2 == 0) ? zA : zB;
    ushort* zout = (k % 2 == 0) ? zB : zA;
    int wl_ofs = 32768 + k * 16384;  // w_lin[k]/w_self[k] (producing layer k+1), k<=4
    if (k == 0) {
      k_fused<1, 1><<<FGRID, 256, 0, stream>>>(row_ptr, srcs, zin, s, wbf, wl_ofs, k,
                                               b_lin, b_self, bias, b_last, out, zout);
    } else if (k < NLAYERS - 1) {
      k_fused<1, 0><<<FGRID, 256, 0, stream>>>(row_ptr, srcs, zin, s, wbf, wl_ofs, k,
                                               b_lin + (size_t)k * 64, b_self + (size_t)k * 64,
                                               bias + (size_t)k * 64, nullptr, out, zout);
    } else {
      k_fused<0, 0><<<FGRID, 256, 0, stream>>>(row_ptr, srcs, zin, s, wbf, 0, k,
                                               nullptr, nullptr, nullptr, nullptr, out, zout);
    }
  }
}